// Round 9
// baseline (69.736 us; speedup 1.0000x reference)
//
#include <hip/hip_runtime.h>

typedef __attribute__((ext_vector_type(8))) short short8;
typedef __attribute__((ext_vector_type(4))) float f32x4;

typedef __attribute__((address_space(1))) const unsigned gas_u32;
typedef __attribute__((address_space(3))) unsigned las_u32;

static __device__ __forceinline__ void g2l16(const void* g, void* l) {
  __builtin_amdgcn_global_load_lds((gas_u32*)g, (las_u32*)l, 16, 0, 0);
}

static __device__ __forceinline__ short f2bf(float f) {
  union { float f; unsigned u; } v; v.f = f;
  unsigned r = (v.u + 0x7FFFu + ((v.u >> 16) & 1u)) >> 16;   // RNE
  return (short)r;
}

#define MF(a_, b_, c_) __builtin_amdgcn_mfma_f32_16x16x32_bf16(a_, b_, c_, 0, 0, 0)

// ---- x fp32 -> bf16 into zero-padded xbp[32][34][34][128], 8 elems/thread ----
static __device__ __forceinline__ void xcvt_body(const float* __restrict__ x,
                                                 short* __restrict__ xbp, int i) {
  int c8 = i & 15;
  int t = i >> 4;
  int wp = t % 34, t2 = t / 34;
  int hp = t2 % 34, b = t2 / 34;
  short8 o = {};
  if (hp >= 1 && hp <= 32 && wp >= 1 && wp <= 32) {
    const f32x4* s = (const f32x4*)(x + (((size_t)((b << 5) + hp - 1) << 5) + (wp - 1)) * 128 + c8 * 8);
    f32x4 a = s[0], bb2 = s[1];
    o[0] = f2bf(a[0]); o[1] = f2bf(a[1]); o[2] = f2bf(a[2]); o[3] = f2bf(a[3]);
    o[4] = f2bf(bb2[0]); o[5] = f2bf(bb2[1]); o[6] = f2bf(bb2[2]); o[7] = f2bf(bb2[3]);
  }
  ((short8*)xbp)[i] = o;
}

// ---- weight prep: maskmul | tmask(k1,m1) | tmask(k2,m2) | xcvt share ----
__global__ __launch_bounds__(256) void k_prepw(const float* __restrict__ k0f,
                                               const float* __restrict__ m0f,
                                               const float* __restrict__ scf,
                                               const float* __restrict__ k1f,
                                               const float* __restrict__ m1f,
                                               const float* __restrict__ k2f,
                                               const float* __restrict__ m2f,
                                               short* __restrict__ w1b,
                                               short* __restrict__ w2T,
                                               short* __restrict__ w3T,
                                               const float* __restrict__ x,
                                               short* __restrict__ xbp) {
  __shared__ float tile[32][33];
  const int bb = blockIdx.x, tid = threadIdx.x;
  if (bb < 648) {
    int i = bb * 256 + tid;
    float s = scf[0];
    const f32x4* kk = (const f32x4*)k0f + (size_t)i * 2;
    const f32x4* mm = (const f32x4*)m0f + (size_t)i * 2;
    f32x4 a0 = kk[0], a1 = kk[1], b0 = mm[0], b1 = mm[1];
    short8 o;
    o[0] = f2bf(a0[0] * b0[0] * s); o[1] = f2bf(a0[1] * b0[1] * s);
    o[2] = f2bf(a0[2] * b0[2] * s); o[3] = f2bf(a0[3] * b0[3] * s);
    o[4] = f2bf(a1[0] * b1[0] * s); o[5] = f2bf(a1[1] * b1[1] * s);
    o[6] = f2bf(a1[2] * b1[2] * s); o[7] = f2bf(a1[3] * b1[3] * s);
    ((short8*)w1b)[i] = o;
  } else if (bb < 1480) {
    const float *kf, *mf; short* outp; int D, F, idx;
    if (bb < 1224) { kf = k1f; mf = m1f; outp = w2T; D = 1152; F = 512; idx = bb - 648; }
    else           { kf = k2f; mf = m2f; outp = w3T; D = 512;  F = 512; idx = bb - 1224; }
    int f0 = (idx & 15) * 32, d0 = (idx >> 4) * 32;
    int tx = tid & 31, ty = tid >> 5;
#pragma unroll
    for (int i = 0; i < 4; ++i) {
      int d = d0 + ty + i * 8;
      size_t ix = (size_t)d * F + f0 + tx;
      tile[ty + i * 8][tx] = kf[ix] * mf[ix];
    }
    __syncthreads();
#pragma unroll
    for (int i = 0; i < 4; ++i) {
      int f = f0 + ty + i * 8;
      outp[(size_t)f * D + d0 + tx] = f2bf(tile[tx][ty + i * 8]);
    }
  } else {
    xcvt_body(x, xbp, (bb - 1480) * 256 + tid);   // xcvt blocks 0..767
  }
}

// ---- bf16 GEMM 64x64 tiles, BK=128 double-buffered prefetch (blocks < 144),
//      merged with x-convert (blocks >= 144) ----
// C[M][N] = A[M][K] @ BT[N][K]^T ; K % 128 == 0
__global__ __launch_bounds__(256) void k_gemmx(const short* __restrict__ A,
                                               const short* __restrict__ BT,
                                               short* __restrict__ C, int M, int N, int K,
                                               const float* __restrict__ x,
                                               short* __restrict__ xbp, int xoff) {
  __shared__ __align__(16) short As[2][64][128];   // 32 KiB
  __shared__ __align__(16) short Bs[2][64][128];   // 32 KiB
  if (blockIdx.x >= 144) {
    xcvt_body(x, xbp, (xoff + (int)blockIdx.x - 144) * 256 + (int)threadIdx.x);
    return;
  }
  const int ntiles = N >> 6;
  const int m0 = (blockIdx.x / ntiles) << 6, n0 = (blockIdx.x % ntiles) << 6;
  const int tid = threadIdx.x;
  const int lane = tid & 63, wv = tid >> 6;
  const int wr = (wv >> 1) * 32, wc = (wv & 1) * 32;
  const int lr = lane & 15, lh = lane >> 4;

  // staging: thread covers 16B slot sl of row rr (+j*16), pre-swizzled source
  const int rr = tid >> 4, sl = tid & 15;
  const int swz = sl ^ (rr & 7);
  const unsigned aOff = (unsigned)(m0 + rr) * K + swz * 8;
  const unsigned bOff = (unsigned)(n0 + rr) * K + swz * 8;
  const int ldsRow = 4 * wv;   // wave-uniform row base; + j*16 per op

  f32x4 acc[2][2] = {};

#define GST(buf_, kt_) do { \
    _Pragma("unroll") for (int j = 0; j < 4; ++j) \
      g2l16(A + aOff + (unsigned)j * 16u * (unsigned)K + (unsigned)(kt_) * 128u, \
            &As[buf_][j * 16 + ldsRow][0]); \
    _Pragma("unroll") for (int j = 0; j < 4; ++j) \
      g2l16(BT + bOff + (unsigned)j * 16u * (unsigned)K + (unsigned)(kt_) * 128u, \
            &Bs[buf_][j * 16 + ldsRow][0]); \
  } while (0)

  const int nk = K >> 7;
  GST(0, 0);
  asm volatile("s_waitcnt vmcnt(0)" ::: "memory");
  __builtin_amdgcn_s_barrier();

  for (int kt = 0; kt < nk; ++kt) {
    const int cur = kt & 1;
    if (kt + 1 < nk) { if (cur) GST(0, kt + 1); else GST(1, kt + 1); }
#pragma unroll
    for (int ks = 0; ks < 4; ++ks) {
      short8 af[2], bf[2];
#pragma unroll
      for (int i = 0; i < 2; ++i)
        af[i] = *(const short8*)&As[cur][wr + i * 16 + lr][((ks * 4 + lh) ^ (lr & 7)) * 8];
#pragma unroll
      for (int i = 0; i < 2; ++i)
        bf[i] = *(const short8*)&Bs[cur][wc + i * 16 + lr][((ks * 4 + lh) ^ (lr & 7)) * 8];
#pragma unroll
      for (int mi = 0; mi < 2; ++mi)
#pragma unroll
        for (int ni = 0; ni < 2; ++ni)
          acc[mi][ni] = MF(af[mi], bf[ni], acc[mi][ni]);
    }
    if (kt + 1 < nk) asm volatile("s_waitcnt vmcnt(0)" ::: "memory");
    __builtin_amdgcn_s_barrier();
  }
#pragma unroll
  for (int mi = 0; mi < 2; ++mi) {
    const int row = m0 + wr + mi * 16 + lh * 4;
#pragma unroll
    for (int ni = 0; ni < 2; ++ni) {
      const int col = n0 + wc + ni * 16 + lr;
#pragma unroll
      for (int q = 0; q < 4; ++q)
        C[(size_t)(row + q) * N + col] = f2bf(acc[mi][ni][q]);
    }
  }
#undef GST
}

// ======== conv: 256x128 tile, single-buffer BK=64, 4-phase, ONE barrier/phase ========
// out[32768][512] = im2col(xbp)[32768][1152] @ wT[512][1152]^T + bias
// Staging shifted one phase later than the quarter it refills (quarter q is read
// ONLY at phase q; B only at phase 0), so the previous phase's barrier already
// orders the last reads of the overwritten rows -> barrier1 is unnecessary.
// Schedule: ph0 stages AQ3(t); ph1 B0,B1(t+1); ph2 AQ0,AQ1(t+1); ph3 AQ2(t+1).
// Uniform vmcnt(2) per phase: the 2 newest outstanding ops are never read next
// phase (checked for all 4 phases + t=0 / t=17 edges).
#define RD_A(mf_, ks_) \
  (*(const short8*)&As[wr * 128 + (mf_) * 16 + lr][(((ks_) * 4 + lh) ^ (lr & 7)) * 8])
#define RD_B(nf_, ks_) \
  (*(const short8*)&Bs[wc * 32 + (nf_) * 16 + lr][(((ks_) * 4 + lh) ^ (lr & 7)) * 8])

#define LOADB do { \
  bfr[0][0] = RD_B(0, 0); bfr[0][1] = RD_B(0, 1); \
  bfr[1][0] = RD_B(1, 0); bfr[1][1] = RD_B(1, 1); } while (0)

// stage A quarter q of K-tile tt (64 LDS rows: {32q..+31} in each 128-half), 1 op/thread
#define STAGE_AQ(q_, tt_) do { \
  const int tc_ = (tt_) > 17 ? 17 : (tt_); \
  const int khw_ = tc_ >> 1; const int kh_ = (khw_ * 11) >> 5; const int kw_ = khw_ - kh_ * 3; \
  const int ao_ = (kh_ * 34 + kw_) * 128 + ((tc_ & 1) << 6) + (q_) * 4352; \
  g2l16(xbp + aBase + ao_, &As[aRow + (q_) * 32][0]); } while (0)

// stage B half j (64 rows) of K-tile tt, 1 op/thread
#define STAGE_BH(j_, tt_) do { \
  const int tc_ = (tt_) > 17 ? 17 : (tt_); \
  g2l16(wT + bBase + (j_) * 73728 + tc_ * 64, &Bs[(j_) * 64 + bRow][0]); } while (0)

#define MFMA8(p_) \
  acc[2*(p_)  ][0] = MF(a0k0, bfr[0][0], acc[2*(p_)  ][0]); \
  acc[2*(p_)  ][1] = MF(a0k0, bfr[1][0], acc[2*(p_)  ][1]); \
  acc[2*(p_)+1][0] = MF(a1k0, bfr[0][0], acc[2*(p_)+1][0]); \
  acc[2*(p_)+1][1] = MF(a1k0, bfr[1][0], acc[2*(p_)+1][1]); \
  acc[2*(p_)  ][0] = MF(a0k1, bfr[0][1], acc[2*(p_)  ][0]); \
  acc[2*(p_)  ][1] = MF(a0k1, bfr[1][1], acc[2*(p_)  ][1]); \
  acc[2*(p_)+1][0] = MF(a1k1, bfr[0][1], acc[2*(p_)+1][0]); \
  acc[2*(p_)+1][1] = MF(a1k1, bfr[1][1], acc[2*(p_)+1][1]);

#define VM2 asm volatile("s_waitcnt vmcnt(2)" ::: "memory")

// phase p: ds_read quarter p frags, issue this phase's stage ops, drain lgkm,
// MFMA, counted vmcnt(2), single barrier.
#define PHASE(p_, PRE, ...) do { \
  PRE; \
  short8 a0k0 = RD_A(2*(p_), 0),   a0k1 = RD_A(2*(p_), 1); \
  short8 a1k0 = RD_A(2*(p_)+1, 0), a1k1 = RD_A(2*(p_)+1, 1); \
  __VA_ARGS__ \
  asm volatile("s_waitcnt lgkmcnt(0)" ::: "memory"); \
  __builtin_amdgcn_sched_barrier(0); \
  __builtin_amdgcn_s_setprio(1); \
  MFMA8(p_) \
  __builtin_amdgcn_s_setprio(0); \
  VM2; \
  __builtin_amdgcn_s_barrier(); \
} while (0)

__global__ __launch_bounds__(512, 4) void k_conv(const short* __restrict__ xbp,
                                                 const short* __restrict__ wT,
                                                 const float* __restrict__ bias,
                                                 float* __restrict__ out) {
  __shared__ __align__(16) short As[256][64];   // 32 KiB
  __shared__ __align__(16) short Bs[128][64];   // 16 KiB
  int bid = blockIdx.x;
  bid = (bid & 7) * 64 + (bid >> 3);            // bijective XCD swizzle (512 % 8 == 0)
  const int mt = bid >> 2, nt = bid & 3;
  const int m0 = mt << 8, n0 = nt << 7;
  const int tid = threadIdx.x;
  const int lane = tid & 63, wid = tid >> 6;    // 8 waves: 2M x 4N
  const int wr = wid >> 2, wc = wid & 3;
  const int lr = lane & 15, lh = lane >> 4;

  f32x4 acc[8][2] = {};
  short8 bfr[2][2];

  // staging geometry (1 g2l16/thread covers 64 LDS rows; 8 rows/wave)
  const int wrB = (wid >> 2) * 128;
  const int rsub = (wid & 3) * 8 + (lane >> 3); // 0..31
  const int sw = (lane & 7) ^ (lane >> 3);      // pre-swizzled 16B slot
  const int aRow = wrB + (wid & 3) * 8;         // wave-uniform LDS row base (A)
  const int bRow = wid * 8;                     // wave-uniform LDS row base (B)

  const int Mb = m0 + wrB + rsub;
  const int b = Mb >> 10, h0 = (Mb >> 5) & 31, w = Mb & 31;
  const unsigned aBase = (unsigned)((b * 34 + h0) * 34 + w) * 128 + sw * 8;
  const unsigned bBase = (unsigned)(n0 + wid * 8 + (lane >> 3)) * 1152 + sw * 8;

  // prologue: stage tile 0's B + A quarters 0..2 (AQ3(0) is staged at ph0)
  STAGE_BH(0, 0); STAGE_BH(1, 0);
  STAGE_AQ(0, 0); STAGE_AQ(1, 0); STAGE_AQ(2, 0);
  asm volatile("s_waitcnt vmcnt(0)" ::: "memory");
  __builtin_amdgcn_s_barrier();

  for (int t = 0; t < 18; ++t) {
    const int tn = t + 1;  // clamped inside STAGE macros (idempotent restage at tail)
    PHASE(0, LOADB, STAGE_AQ(3, t););                    // current tile's q3
    PHASE(1, ,      STAGE_BH(0, tn); STAGE_BH(1, tn););  // next tile's B
    PHASE(2, ,      STAGE_AQ(0, tn); STAGE_AQ(1, tn););  // next tile's q0,q1
    PHASE(3, ,      STAGE_AQ(2, tn););                   // next tile's q2
  }
  asm volatile("s_waitcnt vmcnt(0)" ::: "memory");

  // epilogue: fp32 + bias
  const int orow = m0 + wr * 128, ocol = n0 + wc * 32;
#pragma unroll
  for (int mf = 0; mf < 8; ++mf) {
    const int row = orow + mf * 16 + lh * 4;
#pragma unroll
    for (int nf = 0; nf < 2; ++nf) {
      const int col = ocol + nf * 16 + lr;
      const float bv = bias[col];
#pragma unroll
      for (int q = 0; q < 4; ++q)
        out[(size_t)(row + q) * 512 + col] = acc[mf][nf][q] + bv;
    }
  }
}

extern "C" void kernel_launch(void* const* d_in, const int* in_sizes, int n_in,
                              void* d_out, int out_size, void* d_ws, size_t ws_size,
                              hipStream_t stream) {
  (void)in_sizes; (void)n_in; (void)out_size; (void)ws_size;
  const float* x    = (const float*)d_in[0];
  const float* k0   = (const float*)d_in[1];
  const float* k1   = (const float*)d_in[2];
  const float* k2   = (const float*)d_in[3];
  const float* m0   = (const float*)d_in[4];
  const float* m1   = (const float*)d_in[5];
  const float* m2   = (const float*)d_in[6];
  const float* sc   = (const float*)d_in[7];
  const float* bias = (const float*)d_in[8];
  float* out = (float*)d_out;
  char* ws = (char*)d_ws;

  short* xbp = (short*)(ws);              // 32*34*34*128 bf16 = 9,469,952 B
  short* w1b = (short*)(ws + 9469952);    // 1152*1152 bf16    = 2,654,208 B
  short* w2T = (short*)(ws + 12124160);   // 512*1152 bf16     = 1,179,648 B
  short* w3T = (short*)(ws + 13303808);   // 512*512 bf16      =   524,288 B
  short* A1b = (short*)(ws + 13828096);   // 1152*512 bf16     = 1,179,648 B
  short* wET = (short*)(ws + 15007744);   // 512*1152 bf16     = 1,179,648 B

  // xcvt split: 768 blocks (prepw) + 772 (gemm1) + 772 (gemm2) = 2312 total
  k_prepw<<<2248, 256, 0, stream>>>(k0, m0, sc, k1, m1, k2, m2, w1b, w2T, w3T, x, xbp);
  // A1 (1152x512) = w1 @ w2 (K=1152, 9 BK-stages)  ||  xcvt blocks 768..1539
  k_gemmx<<<916, 256, 0, stream>>>(w1b, w2T, A1b, 1152, 512, 1152, x, xbp, 768);
  // wEffT (512x1152) = w3T @ A1^T (K=512, 4 BK-stages)  ||  xcvt blocks 1540..2311
  k_gemmx<<<916, 256, 0, stream>>>(w3T, A1b, wET, 512, 1152, 512, x, xbp, 1540);
  k_conv<<<512, 512, 0, stream>>>(xbp, wET, bias, out);
}

// Round 10
// 69.285 us; speedup vs baseline: 1.0065x; 1.0065x over previous
//
#include <hip/hip_runtime.h>

typedef __attribute__((ext_vector_type(8))) short short8;
typedef __attribute__((ext_vector_type(4))) float f32x4;

typedef __attribute__((address_space(1))) const unsigned gas_u32;
typedef __attribute__((address_space(3))) unsigned las_u32;

static __device__ __forceinline__ void g2l16(const void* g, void* l) {
  __builtin_amdgcn_global_load_lds((gas_u32*)g, (las_u32*)l, 16, 0, 0);
}

static __device__ __forceinline__ short f2bf(float f) {
  union { float f; unsigned u; } v; v.f = f;
  unsigned r = (v.u + 0x7FFFu + ((v.u >> 16) & 1u)) >> 16;   // RNE
  return (short)r;
}

#define MF(a_, b_, c_) __builtin_amdgcn_mfma_f32_16x16x32_bf16(a_, b_, c_, 0, 0, 0)

// ---- x fp32 -> bf16 into zero-padded xbp[32][34][34][128], 8 elems/thread ----
static __device__ __forceinline__ void xcvt_body(const float* __restrict__ x,
                                                 short* __restrict__ xbp, int i) {
  int c8 = i & 15;
  int t = i >> 4;
  int wp = t % 34, t2 = t / 34;
  int hp = t2 % 34, b = t2 / 34;
  short8 o = {};
  if (hp >= 1 && hp <= 32 && wp >= 1 && wp <= 32) {
    const f32x4* s = (const f32x4*)(x + (((size_t)((b << 5) + hp - 1) << 5) + (wp - 1)) * 128 + c8 * 8);
    f32x4 a = s[0], bb2 = s[1];
    o[0] = f2bf(a[0]); o[1] = f2bf(a[1]); o[2] = f2bf(a[2]); o[3] = f2bf(a[3]);
    o[4] = f2bf(bb2[0]); o[5] = f2bf(bb2[1]); o[6] = f2bf(bb2[2]); o[7] = f2bf(bb2[3]);
  }
  ((short8*)xbp)[i] = o;
}

// ---- weight prep: maskmul | tmask(k1,m1) | tmask(k2,m2) | xcvt share ----
__global__ __launch_bounds__(256) void k_prepw(const float* __restrict__ k0f,
                                               const float* __restrict__ m0f,
                                               const float* __restrict__ scf,
                                               const float* __restrict__ k1f,
                                               const float* __restrict__ m1f,
                                               const float* __restrict__ k2f,
                                               const float* __restrict__ m2f,
                                               short* __restrict__ w1b,
                                               short* __restrict__ w2T,
                                               short* __restrict__ w3T,
                                               const float* __restrict__ x,
                                               short* __restrict__ xbp) {
  __shared__ float tile[32][33];
  const int bb = blockIdx.x, tid = threadIdx.x;
  if (bb < 648) {
    int i = bb * 256 + tid;
    float s = scf[0];
    const f32x4* kk = (const f32x4*)k0f + (size_t)i * 2;
    const f32x4* mm = (const f32x4*)m0f + (size_t)i * 2;
    f32x4 a0 = kk[0], a1 = kk[1], b0 = mm[0], b1 = mm[1];
    short8 o;
    o[0] = f2bf(a0[0] * b0[0] * s); o[1] = f2bf(a0[1] * b0[1] * s);
    o[2] = f2bf(a0[2] * b0[2] * s); o[3] = f2bf(a0[3] * b0[3] * s);
    o[4] = f2bf(a1[0] * b1[0] * s); o[5] = f2bf(a1[1] * b1[1] * s);
    o[6] = f2bf(a1[2] * b1[2] * s); o[7] = f2bf(a1[3] * b1[3] * s);
    ((short8*)w1b)[i] = o;
  } else if (bb < 1480) {
    const float *kf, *mf; short* outp; int D, F, idx;
    if (bb < 1224) { kf = k1f; mf = m1f; outp = w2T; D = 1152; F = 512; idx = bb - 648; }
    else           { kf = k2f; mf = m2f; outp = w3T; D = 512;  F = 512; idx = bb - 1224; }
    int f0 = (idx & 15) * 32, d0 = (idx >> 4) * 32;
    int tx = tid & 31, ty = tid >> 5;
#pragma unroll
    for (int i = 0; i < 4; ++i) {
      int d = d0 + ty + i * 8;
      size_t ix = (size_t)d * F + f0 + tx;
      tile[ty + i * 8][tx] = kf[ix] * mf[ix];
    }
    __syncthreads();
#pragma unroll
    for (int i = 0; i < 4; ++i) {
      int f = f0 + ty + i * 8;
      outp[(size_t)f * D + d0 + tx] = f2bf(tile[tx][ty + i * 8]);
    }
  } else {
    xcvt_body(x, xbp, (bb - 1480) * 256 + tid);   // xcvt blocks 0..767
  }
}

// ---- bf16 GEMM 64x64 tiles, BK=128 double-buffered prefetch (blocks < 144),
//      merged with x-convert (blocks >= 144) ----
__global__ __launch_bounds__(256) void k_gemmx(const short* __restrict__ A,
                                               const short* __restrict__ BT,
                                               short* __restrict__ C, int M, int N, int K,
                                               const float* __restrict__ x,
                                               short* __restrict__ xbp, int xoff) {
  __shared__ __align__(16) short As[2][64][128];   // 32 KiB
  __shared__ __align__(16) short Bs[2][64][128];   // 32 KiB
  if (blockIdx.x >= 144) {
    xcvt_body(x, xbp, (xoff + (int)blockIdx.x - 144) * 256 + (int)threadIdx.x);
    return;
  }
  const int ntiles = N >> 6;
  const int m0 = (blockIdx.x / ntiles) << 6, n0 = (blockIdx.x % ntiles) << 6;
  const int tid = threadIdx.x;
  const int lane = tid & 63, wv = tid >> 6;
  const int wr = (wv >> 1) * 32, wc = (wv & 1) * 32;
  const int lr = lane & 15, lh = lane >> 4;

  const int rr = tid >> 4, sl = tid & 15;
  const int swz = sl ^ (rr & 7);
  const unsigned aOff = (unsigned)(m0 + rr) * K + swz * 8;
  const unsigned bOff = (unsigned)(n0 + rr) * K + swz * 8;
  const int ldsRow = 4 * wv;

  f32x4 acc[2][2] = {};

#define GST(buf_, kt_) do { \
    _Pragma("unroll") for (int j = 0; j < 4; ++j) \
      g2l16(A + aOff + (unsigned)j * 16u * (unsigned)K + (unsigned)(kt_) * 128u, \
            &As[buf_][j * 16 + ldsRow][0]); \
    _Pragma("unroll") for (int j = 0; j < 4; ++j) \
      g2l16(BT + bOff + (unsigned)j * 16u * (unsigned)K + (unsigned)(kt_) * 128u, \
            &Bs[buf_][j * 16 + ldsRow][0]); \
  } while (0)

  const int nk = K >> 7;
  GST(0, 0);
  asm volatile("s_waitcnt vmcnt(0)" ::: "memory");
  __builtin_amdgcn_s_barrier();

  for (int kt = 0; kt < nk; ++kt) {
    const int cur = kt & 1;
    if (kt + 1 < nk) { if (cur) GST(0, kt + 1); else GST(1, kt + 1); }
#pragma unroll
    for (int ks = 0; ks < 4; ++ks) {
      short8 af[2], bf[2];
#pragma unroll
      for (int i = 0; i < 2; ++i)
        af[i] = *(const short8*)&As[cur][wr + i * 16 + lr][((ks * 4 + lh) ^ (lr & 7)) * 8];
#pragma unroll
      for (int i = 0; i < 2; ++i)
        bf[i] = *(const short8*)&Bs[cur][wc + i * 16 + lr][((ks * 4 + lh) ^ (lr & 7)) * 8];
#pragma unroll
      for (int mi = 0; mi < 2; ++mi)
#pragma unroll
        for (int ni = 0; ni < 2; ++ni)
          acc[mi][ni] = MF(af[mi], bf[ni], acc[mi][ni]);
    }
    if (kt + 1 < nk) asm volatile("s_waitcnt vmcnt(0)" ::: "memory");
    __builtin_amdgcn_s_barrier();
  }
#pragma unroll
  for (int mi = 0; mi < 2; ++mi) {
    const int row = m0 + wr + mi * 16 + lh * 4;
#pragma unroll
    for (int ni = 0; ni < 2; ++ni) {
      const int col = n0 + wc + ni * 16 + lr;
#pragma unroll
      for (int q = 0; q < 4; ++q)
        C[(size_t)(row + q) * N + col] = f2bf(acc[mi][ni][q]);
    }
  }
#undef GST
}

// ======== conv: 256x128 tile, 4 waves x (128x64), single-buffer BK=64, 1 barrier/phase ========
// out[32768][512] = im2col(xbp)[32768][1152] @ wT[512][1152]^T + bias
// LDS-BW fix: per wave per K-tile 24 ds_read_b128 / 64 MFMA (was 20/32).
#define RD_A(mf_, ks_) \
  (*(const short8*)&As[wr * 128 + (mf_) * 16 + lr][(((ks_) * 4 + lh) ^ (lr & 7)) * 8])
#define RD_B(nf_, ks_) \
  (*(const short8*)&Bs[wc * 64 + (nf_) * 16 + lr][(((ks_) * 4 + lh) ^ (lr & 7)) * 8])

#define LOADB do { \
  bfr[0][0] = RD_B(0, 0); bfr[0][1] = RD_B(0, 1); \
  bfr[1][0] = RD_B(1, 0); bfr[1][1] = RD_B(1, 1); \
  bfr[2][0] = RD_B(2, 0); bfr[2][1] = RD_B(2, 1); \
  bfr[3][0] = RD_B(3, 0); bfr[3][1] = RD_B(3, 1); } while (0)

// stage A quarter q of K-tile tt (rows {32q..+31} in each 128-half), 2 ops/thread
#define STAGE_AQ(q_, tt_) do { \
  const int tc_ = (tt_) > 17 ? 17 : (tt_); \
  const int khw_ = tc_ >> 1; const int kh_ = (khw_ * 11) >> 5; const int kw_ = khw_ - kh_ * 3; \
  const int ao_ = (kh_ * 34 + kw_) * 128 + ((tc_ & 1) << 6) + (q_) * 4352; \
  g2l16(xbp + aBase + ao_, &As[(q_) * 32 + ldsA][0]); \
  g2l16(xbp + aBase + 17408 + ao_, &As[128 + (q_) * 32 + ldsA][0]); } while (0)

// stage all B (128 rows) of K-tile tt, 4 ops/thread
#define STAGE_B(tt_) do { \
  const int tc_ = (tt_) > 17 ? 17 : (tt_); \
  g2l16(wT + bBase +     tc_ * 64, &Bs[     ldsA][0]); \
  g2l16(wT + bBase + 36864 + tc_ * 64, &Bs[32 + ldsA][0]); \
  g2l16(wT + bBase + 73728 + tc_ * 64, &Bs[64 + ldsA][0]); \
  g2l16(wT + bBase + 110592 + tc_ * 64, &Bs[96 + ldsA][0]); } while (0)

// 16 MFMA: mf pair {2p, 2p+1} x nf 0..3 x ks 0,1
#define MFMA16(p_) \
  acc[2*(p_)  ][0] = MF(a0k0, bfr[0][0], acc[2*(p_)  ][0]); \
  acc[2*(p_)  ][1] = MF(a0k0, bfr[1][0], acc[2*(p_)  ][1]); \
  acc[2*(p_)  ][2] = MF(a0k0, bfr[2][0], acc[2*(p_)  ][2]); \
  acc[2*(p_)  ][3] = MF(a0k0, bfr[3][0], acc[2*(p_)  ][3]); \
  acc[2*(p_)+1][0] = MF(a1k0, bfr[0][0], acc[2*(p_)+1][0]); \
  acc[2*(p_)+1][1] = MF(a1k0, bfr[1][0], acc[2*(p_)+1][1]); \
  acc[2*(p_)+1][2] = MF(a1k0, bfr[2][0], acc[2*(p_)+1][2]); \
  acc[2*(p_)+1][3] = MF(a1k0, bfr[3][0], acc[2*(p_)+1][3]); \
  acc[2*(p_)  ][0] = MF(a0k1, bfr[0][1], acc[2*(p_)  ][0]); \
  acc[2*(p_)  ][1] = MF(a0k1, bfr[1][1], acc[2*(p_)  ][1]); \
  acc[2*(p_)  ][2] = MF(a0k1, bfr[2][1], acc[2*(p_)  ][2]); \
  acc[2*(p_)  ][3] = MF(a0k1, bfr[3][1], acc[2*(p_)  ][3]); \
  acc[2*(p_)+1][0] = MF(a1k1, bfr[0][1], acc[2*(p_)+1][0]); \
  acc[2*(p_)+1][1] = MF(a1k1, bfr[1][1], acc[2*(p_)+1][1]); \
  acc[2*(p_)+1][2] = MF(a1k1, bfr[2][1], acc[2*(p_)+1][2]); \
  acc[2*(p_)+1][3] = MF(a1k1, bfr[3][1], acc[2*(p_)+1][3]);

// phase p: ds_read frags, issue stage ops, drain lgkm, MFMA, counted vmcnt, barrier
#define PHASE(p_, PRE, WAITV, ...) do { \
  PRE; \
  short8 a0k0 = RD_A(2*(p_), 0),   a0k1 = RD_A(2*(p_), 1); \
  short8 a1k0 = RD_A(2*(p_)+1, 0), a1k1 = RD_A(2*(p_)+1, 1); \
  __VA_ARGS__ \
  asm volatile("s_waitcnt lgkmcnt(0)" ::: "memory"); \
  __builtin_amdgcn_sched_barrier(0); \
  __builtin_amdgcn_s_setprio(1); \
  MFMA16(p_) \
  __builtin_amdgcn_s_setprio(0); \
  WAITV; \
  __builtin_amdgcn_s_barrier(); \
} while (0)

#define VM4 asm volatile("s_waitcnt vmcnt(4)" ::: "memory")
#define VM6 asm volatile("s_waitcnt vmcnt(6)" ::: "memory")
#define VM8 asm volatile("s_waitcnt vmcnt(8)" ::: "memory")

__global__ __launch_bounds__(256, 2) void k_conv(const short* __restrict__ xbp,
                                                 const short* __restrict__ wT,
                                                 const float* __restrict__ bias,
                                                 float* __restrict__ out) {
  __shared__ __align__(16) short As[256][64];   // 32 KiB
  __shared__ __align__(16) short Bs[128][64];   // 16 KiB
  int bid = blockIdx.x;
  bid = (bid & 7) * 64 + (bid >> 3);            // bijective XCD swizzle (512 % 8 == 0)
  const int mt = bid >> 2, nt = bid & 3;
  const int m0 = mt << 8, n0 = nt << 7;
  const int tid = threadIdx.x;
  const int lane = tid & 63, wid = tid >> 6;    // 4 waves: 2M x 2N
  const int wr = wid >> 1, wc = wid & 1;
  const int lr = lane & 15, lh = lane >> 4;

  f32x4 acc[8][4] = {};
  short8 bfr[4][2];

  // staging geometry: each g2l16 op = 256 threads x 16B = 32 LDS rows; 8 rows/wave
  const int rsub = tid >> 3;                    // 0..31
  const int sw = (tid & 7) ^ (rsub & 7);        // pre-swizzled 16B slot
  const int ldsA = wid * 8;                     // wave-uniform LDS row base

  const int Mb = m0 + rsub;
  const int b = Mb >> 10, h0 = (Mb >> 5) & 31, w = Mb & 31;
  const unsigned aBase = (unsigned)((b * 34 + h0) * 34 + w) * 128 + sw * 8;
  const unsigned bBase = (unsigned)(n0 + rsub) * 1152 + sw * 8;

  // prologue: B(0) + A quarters 0..2 of tile 0 (AQ3(0) staged at ph0(0))
  STAGE_B(0);
  STAGE_AQ(0, 0); STAGE_AQ(1, 0); STAGE_AQ(2, 0);
  asm volatile("s_waitcnt vmcnt(0)" ::: "memory");
  __builtin_amdgcn_s_barrier();

  for (int t = 0; t < 18; ++t) {
    const int tn = t + 1;  // clamped inside STAGE macros (idempotent restage at tail)
    PHASE(0, LOADB, VM4, STAGE_AQ(3, t););                  // current tile's q3
    PHASE(1, ,      VM6, STAGE_B(tn););                     // next tile's B
    PHASE(2, ,      VM8, STAGE_AQ(0, tn); STAGE_AQ(1, tn);); // next q0,q1
    PHASE(3, ,      VM4, STAGE_AQ(2, tn););                 // next q2
  }
  asm volatile("s_waitcnt vmcnt(0)" ::: "memory");

  // epilogue: fp32 + bias
  const int orow = m0 + wr * 128, ocol = n0 + wc * 64;
#pragma unroll
  for (int mf = 0; mf < 8; ++mf) {
    const int row = orow + mf * 16 + lh * 4;
#pragma unroll
    for (int nf = 0; nf < 4; ++nf) {
      const int col = ocol + nf * 16 + lr;
      const float bv = bias[col];
#pragma unroll
      for (int q = 0; q < 4; ++q)
        out[(size_t)(row + q) * 512 + col] = acc[mf][nf][q] + bv;
    }
  }
}

extern "C" void kernel_launch(void* const* d_in, const int* in_sizes, int n_in,
                              void* d_out, int out_size, void* d_ws, size_t ws_size,
                              hipStream_t stream) {
  (void)in_sizes; (void)n_in; (void)out_size; (void)ws_size;
  const float* x    = (const float*)d_in[0];
  const float* k0   = (const float*)d_in[1];
  const float* k1   = (const float*)d_in[2];
  const float* k2   = (const float*)d_in[3];
  const float* m0   = (const float*)d_in[4];
  const float* m1   = (const float*)d_in[5];
  const float* m2   = (const float*)d_in[6];
  const float* sc   = (const float*)d_in[7];
  const float* bias = (const float*)d_in[8];
  float* out = (float*)d_out;
  char* ws = (char*)d_ws;

  short* xbp = (short*)(ws);              // 32*34*34*128 bf16 = 9,469,952 B
  short* w1b = (short*)(ws + 9469952);    // 1152*1152 bf16    = 2,654,208 B
  short* w2T = (short*)(ws + 12124160);   // 512*1152 bf16     = 1,179,648 B
  short* w3T = (short*)(ws + 13303808);   // 512*512 bf16      =   524,288 B
  short* A1b = (short*)(ws + 13828096);   // 1152*512 bf16     = 1,179,648 B
  short* wET = (short*)(ws + 15007744);   // 512*1152 bf16     = 1,179,648 B

  // xcvt split: 768 blocks (prepw) + 772 (gemm1) + 772 (gemm2) = 2312 total
  k_prepw<<<2248, 256, 0, stream>>>(k0, m0, sc, k1, m1, k2, m2, w1b, w2T, w3T, x, xbp);
  k_gemmx<<<916, 256, 0, stream>>>(w1b, w2T, A1b, 1152, 512, 1152, x, xbp, 768);
  k_gemmx<<<916, 256, 0, stream>>>(w3T, A1b, wET, 512, 1152, 512, x, xbp, 1540);
  k_conv<<<512, 256, 0, stream>>>(xbp, wET, bias, out);
}

// Round 11
// 68.937 us; speedup vs baseline: 1.0116x; 1.0050x over previous
//
#include <hip/hip_runtime.h>

typedef __attribute__((ext_vector_type(8))) short short8;
typedef __attribute__((ext_vector_type(4))) float f32x4;

typedef __attribute__((address_space(1))) const unsigned gas_u32;
typedef __attribute__((address_space(3))) unsigned las_u32;

static __device__ __forceinline__ void g2l16(const void* g, void* l) {
  __builtin_amdgcn_global_load_lds((gas_u32*)g, (las_u32*)l, 16, 0, 0);
}

static __device__ __forceinline__ short f2bf(float f) {
  union { float f; unsigned u; } v; v.f = f;
  unsigned r = (v.u + 0x7FFFu + ((v.u >> 16) & 1u)) >> 16;   // RNE
  return (short)r;
}

#define MF(a_, b_, c_) __builtin_amdgcn_mfma_f32_16x16x32_bf16(a_, b_, c_, 0, 0, 0)

// ---- x fp32 -> bf16 into zero-padded xbp[32][34][34][128], 8 elems/thread ----
static __device__ __forceinline__ void xcvt_body(const float* __restrict__ x,
                                                 short* __restrict__ xbp, int i) {
  int c8 = i & 15;
  int t = i >> 4;
  int wp = t % 34, t2 = t / 34;
  int hp = t2 % 34, b = t2 / 34;
  short8 o = {};
  if (hp >= 1 && hp <= 32 && wp >= 1 && wp <= 32) {
    const f32x4* s = (const f32x4*)(x + (((size_t)((b << 5) + hp - 1) << 5) + (wp - 1)) * 128 + c8 * 8);
    f32x4 a = s[0], bb2 = s[1];
    o[0] = f2bf(a[0]); o[1] = f2bf(a[1]); o[2] = f2bf(a[2]); o[3] = f2bf(a[3]);
    o[4] = f2bf(bb2[0]); o[5] = f2bf(bb2[1]); o[6] = f2bf(bb2[2]); o[7] = f2bf(bb2[3]);
  }
  ((short8*)xbp)[i] = o;
}

// ---- weight prep: maskmul | tmask(k1,m1) | tmask(k2,m2) | xcvt share ----
__global__ __launch_bounds__(256) void k_prepw(const float* __restrict__ k0f,
                                               const float* __restrict__ m0f,
                                               const float* __restrict__ scf,
                                               const float* __restrict__ k1f,
                                               const float* __restrict__ m1f,
                                               const float* __restrict__ k2f,
                                               const float* __restrict__ m2f,
                                               short* __restrict__ w1b,
                                               short* __restrict__ w2T,
                                               short* __restrict__ w3T,
                                               const float* __restrict__ x,
                                               short* __restrict__ xbp) {
  __shared__ float tile[32][33];
  const int bb = blockIdx.x, tid = threadIdx.x;
  if (bb < 648) {
    int i = bb * 256 + tid;
    float s = scf[0];
    const f32x4* kk = (const f32x4*)k0f + (size_t)i * 2;
    const f32x4* mm = (const f32x4*)m0f + (size_t)i * 2;
    f32x4 a0 = kk[0], a1 = kk[1], b0 = mm[0], b1 = mm[1];
    short8 o;
    o[0] = f2bf(a0[0] * b0[0] * s); o[1] = f2bf(a0[1] * b0[1] * s);
    o[2] = f2bf(a0[2] * b0[2] * s); o[3] = f2bf(a0[3] * b0[3] * s);
    o[4] = f2bf(a1[0] * b1[0] * s); o[5] = f2bf(a1[1] * b1[1] * s);
    o[6] = f2bf(a1[2] * b1[2] * s); o[7] = f2bf(a1[3] * b1[3] * s);
    ((short8*)w1b)[i] = o;
  } else if (bb < 1480) {
    const float *kf, *mf; short* outp; int D, F, idx;
    if (bb < 1224) { kf = k1f; mf = m1f; outp = w2T; D = 1152; F = 512; idx = bb - 648; }
    else           { kf = k2f; mf = m2f; outp = w3T; D = 512;  F = 512; idx = bb - 1224; }
    int f0 = (idx & 15) * 32, d0 = (idx >> 4) * 32;
    int tx = tid & 31, ty = tid >> 5;
#pragma unroll
    for (int i = 0; i < 4; ++i) {
      int d = d0 + ty + i * 8;
      size_t ix = (size_t)d * F + f0 + tx;
      tile[ty + i * 8][tx] = kf[ix] * mf[ix];
    }
    __syncthreads();
#pragma unroll
    for (int i = 0; i < 4; ++i) {
      int f = f0 + ty + i * 8;
      outp[(size_t)f * D + d0 + tx] = f2bf(tile[tx][ty + i * 8]);
    }
  } else {
    xcvt_body(x, xbp, (bb - 1480) * 256 + tid);   // xcvt blocks 0..767
  }
}

// ---- bf16 GEMM 64x64 tiles, BK=128 double-buffered prefetch (blocks < 144),
//      merged with x-convert (blocks >= 144) ----
__global__ __launch_bounds__(256) void k_gemmx(const short* __restrict__ A,
                                               const short* __restrict__ BT,
                                               short* __restrict__ C, int M, int N, int K,
                                               const float* __restrict__ x,
                                               short* __restrict__ xbp, int xoff) {
  __shared__ __align__(16) short As[2][64][128];   // 32 KiB
  __shared__ __align__(16) short Bs[2][64][128];   // 32 KiB
  if (blockIdx.x >= 144) {
    xcvt_body(x, xbp, (xoff + (int)blockIdx.x - 144) * 256 + (int)threadIdx.x);
    return;
  }
  const int ntiles = N >> 6;
  const int m0 = (blockIdx.x / ntiles) << 6, n0 = (blockIdx.x % ntiles) << 6;
  const int tid = threadIdx.x;
  const int lane = tid & 63, wv = tid >> 6;
  const int wr = (wv >> 1) * 32, wc = (wv & 1) * 32;
  const int lr = lane & 15, lh = lane >> 4;

  const int rr = tid >> 4, sl = tid & 15;
  const int swz = sl ^ (rr & 7);
  const unsigned aOff = (unsigned)(m0 + rr) * K + swz * 8;
  const unsigned bOff = (unsigned)(n0 + rr) * K + swz * 8;
  const int ldsRow = 4 * wv;

  f32x4 acc[2][2] = {};

#define GST(buf_, kt_) do { \
    _Pragma("unroll") for (int j = 0; j < 4; ++j) \
      g2l16(A + aOff + (unsigned)j * 16u * (unsigned)K + (unsigned)(kt_) * 128u, \
            &As[buf_][j * 16 + ldsRow][0]); \
    _Pragma("unroll") for (int j = 0; j < 4; ++j) \
      g2l16(BT + bOff + (unsigned)j * 16u * (unsigned)K + (unsigned)(kt_) * 128u, \
            &Bs[buf_][j * 16 + ldsRow][0]); \
  } while (0)

  const int nk = K >> 7;
  GST(0, 0);
  asm volatile("s_waitcnt vmcnt(0)" ::: "memory");
  __builtin_amdgcn_s_barrier();

  for (int kt = 0; kt < nk; ++kt) {
    const int cur = kt & 1;
    if (kt + 1 < nk) { if (cur) GST(0, kt + 1); else GST(1, kt + 1); }
#pragma unroll
    for (int ks = 0; ks < 4; ++ks) {
      short8 af[2], bf[2];
#pragma unroll
      for (int i = 0; i < 2; ++i)
        af[i] = *(const short8*)&As[cur][wr + i * 16 + lr][((ks * 4 + lh) ^ (lr & 7)) * 8];
#pragma unroll
      for (int i = 0; i < 2; ++i)
        bf[i] = *(const short8*)&Bs[cur][wc + i * 16 + lr][((ks * 4 + lh) ^ (lr & 7)) * 8];
#pragma unroll
      for (int mi = 0; mi < 2; ++mi)
#pragma unroll
        for (int ni = 0; ni < 2; ++ni)
          acc[mi][ni] = MF(af[mi], bf[ni], acc[mi][ni]);
    }
    if (kt + 1 < nk) asm volatile("s_waitcnt vmcnt(0)" ::: "memory");
    __builtin_amdgcn_s_barrier();
  }
#pragma unroll
  for (int mi = 0; mi < 2; ++mi) {
    const int row = m0 + wr + mi * 16 + lh * 4;
#pragma unroll
    for (int ni = 0; ni < 2; ++ni) {
      const int col = n0 + wc + ni * 16 + lr;
#pragma unroll
      for (int q = 0; q < 4; ++q)
        C[(size_t)(row + q) * N + col] = f2bf(acc[mi][ni][q]);
    }
  }
#undef GST
}

// ======== conv: 256x128 tile, 4 waves x (128x64), reg-pipelined frag reads ========
// out[32768][512] = im2col(xbp)[32768][1152] @ wT[512][1152]^T + bias
// Phase p consumes A-frags read at phase p-1 (ping-pong aA/aB reg sets), so the
// compiler-inserted lgkm wait lands after a full MFMA window. Staging one phase
// earlier than R10 (legal: pipelined reads retire rows earlier):
//   ph0: AQ0(t+1)   ph1: B(t+1)+AQ1(t+1)   ph2: AQ2(t+1)   ph3: AQ3(t+1)
// => uniform 3-phase stage->read slack. End-of-phase waits VM4/VM8/VM8/VM4
// (steady-state queue walk verified: each read's staging retired exactly on time).
#define RD_A(mf_, ks_) \
  (*(const short8*)&As[wr * 128 + (mf_) * 16 + lr][(((ks_) * 4 + lh) ^ (lr & 7)) * 8])
#define RD_B(nf_, ks_) \
  (*(const short8*)&Bs[wc * 64 + (nf_) * 16 + lr][(((ks_) * 4 + lh) ^ (lr & 7)) * 8])

// stage A quarter q of K-tile tt (rows {32q..+31} in each 128-half), 2 ops/thread
#define STAGE_AQ(q_, tt_) do { \
  const int tc_ = (tt_) > 17 ? 17 : (tt_); \
  const int khw_ = tc_ >> 1; const int kh_ = (khw_ * 11) >> 5; const int kw_ = khw_ - kh_ * 3; \
  const int ao_ = (kh_ * 34 + kw_) * 128 + ((tc_ & 1) << 6) + (q_) * 4352; \
  g2l16(xbp + aBase + ao_, &As[(q_) * 32 + ldsA][0]); \
  g2l16(xbp + aBase + 17408 + ao_, &As[128 + (q_) * 32 + ldsA][0]); } while (0)

// stage all B (128 rows) of K-tile tt, 4 ops/thread
#define STAGE_B(tt_) do { \
  const int tc_ = (tt_) > 17 ? 17 : (tt_); \
  g2l16(wT + bBase +          tc_ * 64, &Bs[     ldsA][0]); \
  g2l16(wT + bBase +  36864 + tc_ * 64, &Bs[32 + ldsA][0]); \
  g2l16(wT + bBase +  73728 + tc_ * 64, &Bs[64 + ldsA][0]); \
  g2l16(wT + bBase + 110592 + tc_ * 64, &Bs[96 + ldsA][0]); } while (0)

// 16 MFMA for phase p using frag regs x0..x3 = {mf_even k0, mf_even k1, mf_odd k0, mf_odd k1}
#define MFMA_PH(p_, x0_, x1_, x2_, x3_) \
  acc[2*(p_)  ][0] = MF(x0_, bfr[0][0], acc[2*(p_)  ][0]); \
  acc[2*(p_)  ][1] = MF(x0_, bfr[1][0], acc[2*(p_)  ][1]); \
  acc[2*(p_)  ][2] = MF(x0_, bfr[2][0], acc[2*(p_)  ][2]); \
  acc[2*(p_)  ][3] = MF(x0_, bfr[3][0], acc[2*(p_)  ][3]); \
  acc[2*(p_)+1][0] = MF(x2_, bfr[0][0], acc[2*(p_)+1][0]); \
  acc[2*(p_)+1][1] = MF(x2_, bfr[1][0], acc[2*(p_)+1][1]); \
  acc[2*(p_)+1][2] = MF(x2_, bfr[2][0], acc[2*(p_)+1][2]); \
  acc[2*(p_)+1][3] = MF(x2_, bfr[3][0], acc[2*(p_)+1][3]); \
  acc[2*(p_)  ][0] = MF(x1_, bfr[0][1], acc[2*(p_)  ][0]); \
  acc[2*(p_)  ][1] = MF(x1_, bfr[1][1], acc[2*(p_)  ][1]); \
  acc[2*(p_)  ][2] = MF(x1_, bfr[2][1], acc[2*(p_)  ][2]); \
  acc[2*(p_)  ][3] = MF(x1_, bfr[3][1], acc[2*(p_)  ][3]); \
  acc[2*(p_)+1][0] = MF(x3_, bfr[0][1], acc[2*(p_)+1][0]); \
  acc[2*(p_)+1][1] = MF(x3_, bfr[1][1], acc[2*(p_)+1][1]); \
  acc[2*(p_)+1][2] = MF(x3_, bfr[2][1], acc[2*(p_)+1][2]); \
  acc[2*(p_)+1][3] = MF(x3_, bfr[3][1], acc[2*(p_)+1][3]);

#define VM4 asm volatile("s_waitcnt vmcnt(4)" ::: "memory")
#define VM8 asm volatile("s_waitcnt vmcnt(8)" ::: "memory")
#define SBAR __builtin_amdgcn_s_barrier()
#define SCHED0 __builtin_amdgcn_sched_barrier(0)

__global__ __launch_bounds__(256, 2) void k_conv(const short* __restrict__ xbp,
                                                 const short* __restrict__ wT,
                                                 const float* __restrict__ bias,
                                                 float* __restrict__ out) {
  __shared__ __align__(16) short As[256][64];   // 32 KiB
  __shared__ __align__(16) short Bs[128][64];   // 16 KiB
  int bid = blockIdx.x;
  bid = (bid & 7) * 64 + (bid >> 3);            // bijective XCD swizzle (512 % 8 == 0)
  const int mt = bid >> 2, nt = bid & 3;
  const int m0 = mt << 8, n0 = nt << 7;
  const int tid = threadIdx.x;
  const int lane = tid & 63, wid = tid >> 6;    // 4 waves: 2M x 2N
  const int wr = wid >> 1, wc = wid & 1;
  const int lr = lane & 15, lh = lane >> 4;

  f32x4 acc[8][4] = {};
  short8 bfr[4][2];
  short8 aA0, aA1, aA2, aA3, aB0, aB1, aB2, aB3;

  // staging geometry: each g2l16 op = 256 threads x 16B = 32 LDS rows; 8 rows/wave
  const int rsub = tid >> 3;                    // 0..31
  const int sw = (tid & 7) ^ (rsub & 7);        // pre-swizzled 16B slot
  const int ldsA = wid * 8;                     // wave-uniform LDS row base

  const int Mb = m0 + rsub;
  const int b = Mb >> 10, h0 = (Mb >> 5) & 31, w = Mb & 31;
  const unsigned aBase = (unsigned)((b * 34 + h0) * 34 + w) * 128 + sw * 8;
  const unsigned bBase = (unsigned)(n0 + rsub) * 1152 + sw * 8;

  // prologue: stage tile 0 fully; drain; read q0(0) frags (waited at ph0's MFMA)
  STAGE_B(0);
  STAGE_AQ(0, 0); STAGE_AQ(1, 0); STAGE_AQ(2, 0); STAGE_AQ(3, 0);
  asm volatile("s_waitcnt vmcnt(0)" ::: "memory");
  SBAR;
  aA0 = RD_A(0, 0); aA1 = RD_A(0, 1); aA2 = RD_A(1, 0); aA3 = RD_A(1, 1);

  for (int t = 0; t < 18; ++t) {
    const int tn = t + 1;  // clamped inside STAGE macros (idempotent restage at tail)
    { // ph0: consume q0(aA)+B(t) [B read now, k0 first]; read q1->aB; stage AQ0(tn)
      bfr[0][0] = RD_B(0, 0); bfr[1][0] = RD_B(1, 0); bfr[2][0] = RD_B(2, 0); bfr[3][0] = RD_B(3, 0);
      bfr[0][1] = RD_B(0, 1); bfr[1][1] = RD_B(1, 1); bfr[2][1] = RD_B(2, 1); bfr[3][1] = RD_B(3, 1);
      aB0 = RD_A(2, 0); aB1 = RD_A(2, 1); aB2 = RD_A(3, 0); aB3 = RD_A(3, 1);
      STAGE_AQ(0, tn);
      SCHED0;
      __builtin_amdgcn_s_setprio(1);
      MFMA_PH(0, aA0, aA1, aA2, aA3)
      __builtin_amdgcn_s_setprio(0);
      VM4; SBAR;
    }
    { // ph1: consume q1(aB); read q2->aA; stage B(tn)+AQ1(tn)
      aA0 = RD_A(4, 0); aA1 = RD_A(4, 1); aA2 = RD_A(5, 0); aA3 = RD_A(5, 1);
      STAGE_B(tn); STAGE_AQ(1, tn);
      SCHED0;
      __builtin_amdgcn_s_setprio(1);
      MFMA_PH(1, aB0, aB1, aB2, aB3)
      __builtin_amdgcn_s_setprio(0);
      VM8; SBAR;
    }
    { // ph2: consume q2(aA); read q3->aB; stage AQ2(tn)
      aB0 = RD_A(6, 0); aB1 = RD_A(6, 1); aB2 = RD_A(7, 0); aB3 = RD_A(7, 1);
      STAGE_AQ(2, tn);
      SCHED0;
      __builtin_amdgcn_s_setprio(1);
      MFMA_PH(2, aA0, aA1, aA2, aA3)
      __builtin_amdgcn_s_setprio(0);
      VM8; SBAR;
    }
    { // ph3: consume q3(aB); read q0(t+1)->aA (staged ph0(t), retired by ph2's VM8); stage AQ3(tn)
      aA0 = RD_A(0, 0); aA1 = RD_A(0, 1); aA2 = RD_A(1, 0); aA3 = RD_A(1, 1);
      STAGE_AQ(3, tn);
      SCHED0;
      __builtin_amdgcn_s_setprio(1);
      MFMA_PH(3, aB0, aB1, aB2, aB3)
      __builtin_amdgcn_s_setprio(0);
      VM4; SBAR;
    }
  }
  asm volatile("s_waitcnt vmcnt(0)" ::: "memory");

  // epilogue: fp32 + bias
  const int orow = m0 + wr * 128, ocol = n0 + wc * 64;
#pragma unroll
  for (int mf = 0; mf < 8; ++mf) {
    const int row = orow + mf * 16 + lh * 4;
#pragma unroll
    for (int nf = 0; nf < 4; ++nf) {
      const int col = ocol + nf * 16 + lr;
      const float bv = bias[col];
#pragma unroll
      for (int q = 0; q < 4; ++q)
        out[(size_t)(row + q) * 512 + col] = acc[mf][nf][q] + bv;
    }
  }
}

extern "C" void kernel_launch(void* const* d_in, const int* in_sizes, int n_in,
                              void* d_out, int out_size, void* d_ws, size_t ws_size,
                              hipStream_t stream) {
  (void)in_sizes; (void)n_in; (void)out_size; (void)ws_size;
  const float* x    = (const float*)d_in[0];
  const float* k0   = (const float*)d_in[1];
  const float* k1   = (const float*)d_in[2];
  const float* k2   = (const float*)d_in[3];
  const float* m0   = (const float*)d_in[4];
  const float* m1   = (const float*)d_in[5];
  const float* m2   = (const float*)d_in[6];
  const float* sc   = (const float*)d_in[7];
  const float* bias = (const float*)d_in[8];
  float* out = (float*)d_out;
  char* ws = (char*)d_ws;

  short* xbp = (short*)(ws);              // 32*34*34*128 bf16 = 9,469,952 B
  short* w1b = (short*)(ws + 9469952);    // 1152*1152 bf16    = 2,654,208 B
  short* w2T = (short*)(ws + 12124160);   // 512*1152 bf16     = 1,179,648 B
  short* w3T = (short*)(ws + 13303808);   // 512*512 bf16      =   524,288 B
  short* A1b = (short*)(ws + 13828096);   // 1152*512 bf16     = 1,179,648 B
  short* wET = (short*)(ws + 15007744);   // 512*1152 bf16     = 1,179,648 B

  // xcvt split: 768 blocks (prepw) + 772 (gemm1) + 772 (gemm2) = 2312 total
  k_prepw<<<2248, 256, 0, stream>>>(k0, m0, sc, k1, m1, k2, m2, w1b, w2T, w3T, x, xbp);
  k_gemmx<<<916, 256, 0, stream>>>(w1b, w2T, A1b, 1152, 512, 1152, x, xbp, 768);
  k_gemmx<<<916, 256, 0, stream>>>(w3T, A1b, wET, 512, 1152, 512, x, xbp, 1540);
  k_conv<<<512, 256, 0, stream>>>(xbp, wET, bias, out);
}